// Round 1
// baseline (659.302 us; speedup 1.0000x reference)
//
#include <hip/hip_runtime.h>

// GCN x2 + final linear, N=100k nodes, E=1.6M edges, feat=128, fp32.
// Pipeline per call (graph-capture safe, all async on `stream`):
//   1) deg count (int atomics) -> dinv = rsqrt(deg+1)
//   2) exclusive scan -> rowptr ; fill dst-CSR (col = src ids)
//   3) layer1: GEMM (x@W1)*dinv[row] -> A ; aggregate A -> B (bias+relu)
//   4) layer2: GEMM (B@W2)*dinv[row] -> A ; aggregate+final-dot -> d_out
// Aggregation is gather-only (one wave per node, CSR), no float atomics.

#define FEAT 128

static inline size_t align_up(size_t x, size_t a){ return (x + a - 1) & ~(a - 1); }

// ---------------- CSR build ----------------

__global__ void count_deg_kernel(const int* __restrict__ dst, int* __restrict__ deg, int E){
  int i = blockIdx.x * blockDim.x + threadIdx.x;
  if (i < E) atomicAdd(&deg[dst[i]], 1);
}

__global__ void dinv_kernel(const int* __restrict__ deg, float* __restrict__ dinv, int N){
  int i = blockIdx.x * blockDim.x + threadIdx.x;
  if (i < N) dinv[i] = rsqrtf((float)(deg[i] + 1));  // +1 self-loop; deg>=1 always
}

// Hillis-Steele block scans: inclusive per 1024-chunk, then scan chunk sums.
__global__ void scan1_kernel(const int* __restrict__ deg, int* __restrict__ rowptr,
                             int* __restrict__ partials, int N){
  __shared__ int sh[1024];
  int t = threadIdx.x;
  int i = blockIdx.x * 1024 + t;
  int v = (i < N) ? deg[i] : 0;
  sh[t] = v;
  __syncthreads();
  #pragma unroll
  for (int off = 1; off < 1024; off <<= 1){
    int add = (t >= off) ? sh[t - off] : 0;
    __syncthreads();
    sh[t] += add;
    __syncthreads();
  }
  if (i < N) rowptr[i + 1] = sh[t];              // inclusive within chunk
  if (t == 1023) partials[blockIdx.x] = sh[t];   // chunk total
}

__global__ void scan2_kernel(int* __restrict__ partials, int nb){
  __shared__ int sh[1024];
  int t = threadIdx.x;
  int v = (t < nb) ? partials[t] : 0;
  sh[t] = v;
  __syncthreads();
  #pragma unroll
  for (int off = 1; off < 1024; off <<= 1){
    int add = (t >= off) ? sh[t - off] : 0;
    __syncthreads();
    sh[t] += add;
    __syncthreads();
  }
  if (t < nb) partials[t] = sh[t] - v;           // exclusive chunk offsets
}

__global__ void scan3_kernel(int* __restrict__ rowptr, const int* __restrict__ partials, int N){
  int i = blockIdx.x * blockDim.x + threadIdx.x;
  if (i < N) rowptr[i + 1] += partials[i >> 10];
  if (i == 0) rowptr[0] = 0;
}

__global__ void fill_csr_kernel(const int* __restrict__ src, const int* __restrict__ dst,
                                const int* __restrict__ rowptr, int* __restrict__ cursor,
                                int* __restrict__ col, int E){
  int i = blockIdx.x * blockDim.x + threadIdx.x;
  if (i < E){
    int d = dst[i];
    int pos = rowptr[d] + atomicAdd(&cursor[d], 1);
    col[pos] = src[i];
  }
}

// ---------------- GEMM: C[row] = (A[row] @ W) * dinv[row] ----------------
// 128x128 tile per 256-thread block; each thread: 8x8 register tile.
// A-tile staged transposed in LDS so per-k reads are 2x b128 per operand.

__global__ __launch_bounds__(256) void gemm128_scaled_kernel(
    const float* __restrict__ A, const float* __restrict__ W,
    const float* __restrict__ dinv, float* __restrict__ C, int N)
{
  const int t  = threadIdx.x;
  const int tx = t & 15;        // col group: cols tx*8..+7
  const int ty = t >> 4;        // row group: rows ty*8..+7
  const int row0 = blockIdx.x * 128;

  __shared__ float aT[16][132]; // aT[kk][r] = A[row0+r][k0+kk]  (pad 132: bank spread)
  __shared__ float wS[16][132]; // wS[kk][c] = W[k0+kk][c]

  float acc[8][8];
  #pragma unroll
  for (int r = 0; r < 8; ++r)
    #pragma unroll
    for (int c = 0; c < 8; ++c) acc[r][c] = 0.f;

  for (int k0 = 0; k0 < FEAT; k0 += 16){
    #pragma unroll
    for (int j = 0; j < 8; ++j){              // A tile: 128 rows x 16 k
      int r   = ty + j * 16;
      int row = row0 + r;
      float v = 0.f;
      if (row < N) v = A[(size_t)row * FEAT + k0 + tx];
      aT[tx][r] = v;
    }
    #pragma unroll
    for (int i = 0; i < 8; ++i){              // W tile: 16 k x 128 cols, coalesced
      int idx = t + i * 256;
      wS[idx >> 7][idx & 127] = W[(size_t)(k0 + (idx >> 7)) * FEAT + (idx & 127)];
    }
    __syncthreads();
    #pragma unroll
    for (int kk = 0; kk < 16; ++kk){
      float a[8], b[8];
      #pragma unroll
      for (int r = 0; r < 8; ++r) a[r] = aT[kk][ty * 8 + r];
      #pragma unroll
      for (int c = 0; c < 8; ++c) b[c] = wS[kk][tx * 8 + c];
      #pragma unroll
      for (int r = 0; r < 8; ++r)
        #pragma unroll
        for (int c = 0; c < 8; ++c) acc[r][c] += a[r] * b[c];
    }
    __syncthreads();
  }

  #pragma unroll
  for (int r = 0; r < 8; ++r){
    int row = row0 + ty * 8 + r;
    if (row < N){
      float s = dinv[row];
      float* p = &C[(size_t)row * FEAT + tx * 8];
      float4 v0 = make_float4(acc[r][0]*s, acc[r][1]*s, acc[r][2]*s, acc[r][3]*s);
      float4 v1 = make_float4(acc[r][4]*s, acc[r][5]*s, acc[r][6]*s, acc[r][7]*s);
      *reinterpret_cast<float4*>(p)     = v0;
      *reinterpret_cast<float4*>(p + 4) = v1;
    }
  }
}

// ---------------- Aggregation: out[v] = relu(dinv[v]*(Hs[v] + sum Hs[u]) + b) ----
// One wave per node; lane owns 2 features (float2 = 512B/row coalesced).

__global__ __launch_bounds__(256) void aggregate_kernel(
    const float* __restrict__ Hs, const int* __restrict__ rowptr,
    const int* __restrict__ col, const float* __restrict__ dinv,
    const float* __restrict__ bias, float* __restrict__ out, int N)
{
  int gid  = blockIdx.x * blockDim.x + threadIdx.x;
  int v    = gid >> 6;
  int lane = threadIdx.x & 63;
  if (v >= N) return;
  const float dv = dinv[v];
  int e = rowptr[v], end = rowptr[v + 1];

  float2 acc = *reinterpret_cast<const float2*>(Hs + (size_t)v * FEAT + lane * 2); // self-loop
  for (; e + 4 <= end; e += 4){
    int u0 = col[e], u1 = col[e+1], u2 = col[e+2], u3 = col[e+3];
    float2 p0 = *reinterpret_cast<const float2*>(Hs + (size_t)u0 * FEAT + lane * 2);
    float2 p1 = *reinterpret_cast<const float2*>(Hs + (size_t)u1 * FEAT + lane * 2);
    float2 p2 = *reinterpret_cast<const float2*>(Hs + (size_t)u2 * FEAT + lane * 2);
    float2 p3 = *reinterpret_cast<const float2*>(Hs + (size_t)u3 * FEAT + lane * 2);
    acc.x += p0.x + p1.x + p2.x + p3.x;
    acc.y += p0.y + p1.y + p2.y + p3.y;
  }
  for (; e < end; ++e){
    int u = col[e];
    float2 p = *reinterpret_cast<const float2*>(Hs + (size_t)u * FEAT + lane * 2);
    acc.x += p.x; acc.y += p.y;
  }
  float2 b = *reinterpret_cast<const float2*>(bias + lane * 2);
  float2 o = make_float2(fmaxf(dv * acc.x + b.x, 0.f), fmaxf(dv * acc.y + b.y, 0.f));
  *reinterpret_cast<float2*>(out + (size_t)v * FEAT + lane * 2) = o;
}

// Layer-2 aggregate fused with the final 128->1 linear (+wave reduce).
__global__ __launch_bounds__(256) void aggregate_final_kernel(
    const float* __restrict__ Hs, const int* __restrict__ rowptr,
    const int* __restrict__ col, const float* __restrict__ dinv,
    const float* __restrict__ bias, const float* __restrict__ Wf,
    const float* __restrict__ bf, float* __restrict__ out, int N)
{
  int gid  = blockIdx.x * blockDim.x + threadIdx.x;
  int v    = gid >> 6;
  int lane = threadIdx.x & 63;
  if (v >= N) return;
  const float dv = dinv[v];
  int e = rowptr[v], end = rowptr[v + 1];

  float2 acc = *reinterpret_cast<const float2*>(Hs + (size_t)v * FEAT + lane * 2);
  for (; e + 4 <= end; e += 4){
    int u0 = col[e], u1 = col[e+1], u2 = col[e+2], u3 = col[e+3];
    float2 p0 = *reinterpret_cast<const float2*>(Hs + (size_t)u0 * FEAT + lane * 2);
    float2 p1 = *reinterpret_cast<const float2*>(Hs + (size_t)u1 * FEAT + lane * 2);
    float2 p2 = *reinterpret_cast<const float2*>(Hs + (size_t)u2 * FEAT + lane * 2);
    float2 p3 = *reinterpret_cast<const float2*>(Hs + (size_t)u3 * FEAT + lane * 2);
    acc.x += p0.x + p1.x + p2.x + p3.x;
    acc.y += p0.y + p1.y + p2.y + p3.y;
  }
  for (; e < end; ++e){
    int u = col[e];
    float2 p = *reinterpret_cast<const float2*>(Hs + (size_t)u * FEAT + lane * 2);
    acc.x += p.x; acc.y += p.y;
  }
  float2 b = *reinterpret_cast<const float2*>(bias + lane * 2);
  float ox = fmaxf(dv * acc.x + b.x, 0.f);
  float oy = fmaxf(dv * acc.y + b.y, 0.f);
  float2 w = *reinterpret_cast<const float2*>(Wf + lane * 2);
  float p = ox * w.x + oy * w.y;
  #pragma unroll
  for (int off = 32; off > 0; off >>= 1) p += __shfl_down(p, off, 64);
  if (lane == 0) out[v] = p + bf[0];
}

// ---------------- launch ----------------

extern "C" void kernel_launch(void* const* d_in, const int* in_sizes, int n_in,
                              void* d_out, int out_size, void* d_ws, size_t ws_size,
                              hipStream_t stream)
{
  const float* x   = (const float*)d_in[0];
  const float* W1  = (const float*)d_in[1];
  const float* b1  = (const float*)d_in[2];
  const float* W2  = (const float*)d_in[3];
  const float* b2  = (const float*)d_in[4];
  const float* Wf  = (const float*)d_in[5];
  const float* bfb = (const float*)d_in[6];
  const int*  eidx = (const int*)d_in[7];

  const int N = in_sizes[0] / FEAT;
  const int E = in_sizes[7] / 2;
  const int* src = eidx;
  const int* dst = eidx + E;

  char* ws = (char*)d_ws;
  size_t off = 0;
  auto alloc = [&](size_t bytes){ void* p = ws + off; off = align_up(off + bytes, 256); return p; };
  float* A      = (float*)alloc((size_t)N * FEAT * 4);   // 51.2 MB
  float* B      = (float*)alloc((size_t)N * FEAT * 4);   // 51.2 MB
  int*   deg    = (int*)  alloc((size_t)N * 4);
  int*   cursor = (int*)  alloc((size_t)N * 4);
  float* dinv   = (float*)alloc((size_t)N * 4);
  int*   rowptr = (int*)  alloc((size_t)(N + 1) * 4);
  int*   colidx = (int*)  alloc((size_t)E * 4);          // 6.4 MB
  int*   parts  = (int*)  alloc(1024 * 4);
  (void)ws_size; (void)n_in; (void)out_size;

  const int tb = 256;
  hipMemsetAsync(deg,    0, (size_t)N * 4, stream);
  hipMemsetAsync(cursor, 0, (size_t)N * 4, stream);

  count_deg_kernel<<<(E + tb - 1) / tb, tb, 0, stream>>>(dst, deg, E);
  dinv_kernel<<<(N + tb - 1) / tb, tb, 0, stream>>>(deg, dinv, N);

  int nb = (N + 1023) / 1024;                 // 98 chunks (<=1024 required)
  scan1_kernel<<<nb, 1024, 0, stream>>>(deg, rowptr, parts, N);
  scan2_kernel<<<1, 1024, 0, stream>>>(parts, nb);
  scan3_kernel<<<(N + tb - 1) / tb, tb, 0, stream>>>(rowptr, parts, N);
  fill_csr_kernel<<<(E + tb - 1) / tb, tb, 0, stream>>>(src, dst, rowptr, cursor, colidx, E);

  int gblocks = (N + 127) / 128;
  int ablocks = ((size_t)N * 64 + tb - 1) / tb;   // one wave per node

  gemm128_scaled_kernel<<<gblocks, 256, 0, stream>>>(x, W1, dinv, A, N);
  aggregate_kernel<<<ablocks, tb, 0, stream>>>(A, rowptr, colidx, dinv, b1, B, N);
  gemm128_scaled_kernel<<<gblocks, 256, 0, stream>>>(B, W2, dinv, A, N);
  aggregate_final_kernel<<<ablocks, tb, 0, stream>>>(A, rowptr, colidx, dinv, b2, Wf, bfb,
                                                     (float*)d_out, N);
}

// Round 3
// 538.319 us; speedup vs baseline: 1.2247x; 1.2247x over previous
//
#include <hip/hip_runtime.h>

// GCN x2 + final linear, N=100k nodes, E=1.6M edges, feat=128, fp32.
// CSR build = two-level radix partition by dst (bucket = dst>>9, 512 nodes):
//   K1 bin_count   : per-block LDS histogram -> global bucket counts
//   K2 bucket_scan : exclusive scan of 196 bucket counts (+init cursors, rowptr[N])
//   K3 bin_scatter : append packed (src<<9 | dst&511) into bucket streams
//   K4 bucket_build: per bucket (1 block): local deg -> dinv, rowptr, colidx
// Then: GEMM (x@W)*dinv[row] -> aggregate (gather CSR, bias+relu) x2,
// layer-2 aggregate fused with the final 128->1 dot.

#define FEAT 128
#define BSH 9            // 512 nodes per bucket
#define BNODES 512

static inline size_t align_up(size_t x, size_t a){ return (x + a - 1) & ~(a - 1); }

// ---------------- CSR build via radix partition ----------------

__global__ __launch_bounds__(256) void bin_count_kernel(
    const int* __restrict__ dst, int* __restrict__ bucket_cnt, int E, int chunk)
{
  __shared__ int hist[256];
  int t = threadIdx.x;
  hist[t] = 0;
  __syncthreads();
  int s0 = blockIdx.x * chunk, s1 = min(E, s0 + chunk);
  for (int i = s0 + t; i < s1; i += 256) atomicAdd(&hist[dst[i] >> BSH], 1);
  __syncthreads();
  if (hist[t] > 0) atomicAdd(&bucket_cnt[t], hist[t]);
}

__global__ __launch_bounds__(256) void bucket_scan_kernel(
    int* __restrict__ bucket_cnt, int* __restrict__ bucket_off,
    int* __restrict__ bucket_cur, int* __restrict__ rowptr, int nbk, int N)
{
  __shared__ int sh[256];
  int t = threadIdx.x;
  int v = (t < nbk) ? bucket_cnt[t] : 0;
  sh[t] = v;
  __syncthreads();
  #pragma unroll
  for (int off = 1; off < 256; off <<= 1){
    int add = (t >= off) ? sh[t - off] : 0;
    __syncthreads();
    sh[t] += add;
    __syncthreads();
  }
  if (t < nbk){
    int e = sh[t] - v;               // exclusive
    bucket_off[t] = e;
    bucket_cur[t] = e;
  }
  if (t == 0){
    int total = sh[255];             // all counts beyond nbk are 0
    bucket_off[nbk] = total;
    rowptr[N] = total;
  }
}

__global__ __launch_bounds__(256) void bin_scatter_kernel(
    const int* __restrict__ src, const int* __restrict__ dst,
    int* __restrict__ bucket_cur, unsigned int* __restrict__ packed, int E, int chunk)
{
  __shared__ int hist[256];
  __shared__ int base[256];
  int t = threadIdx.x;
  hist[t] = 0;
  __syncthreads();
  int s0 = blockIdx.x * chunk, s1 = min(E, s0 + chunk);
  for (int i = s0 + t; i < s1; i += 256) atomicAdd(&hist[dst[i] >> BSH], 1);
  __syncthreads();
  int h = hist[t];
  if (h > 0) base[t] = atomicAdd(&bucket_cur[t], h);
  __syncthreads();
  hist[t] = 0;                       // reuse as per-block bucket cursor
  __syncthreads();
  for (int i = s0 + t; i < s1; i += 256){
    int d = dst[i];
    int b = d >> BSH;
    int pos = base[b] + atomicAdd(&hist[b], 1);
    packed[pos] = ((unsigned int)src[i] << BSH) | (unsigned int)(d & (BNODES - 1));
  }
}

__global__ __launch_bounds__(512) void bucket_build_kernel(
    const unsigned int* __restrict__ packed, const int* __restrict__ bucket_off,
    float* __restrict__ dinv, int* __restrict__ rowptr, int* __restrict__ colidx, int N)
{
  __shared__ int degl[BNODES];
  __shared__ int scan[BNODES];
  __shared__ int cur[BNODES];
  int b = blockIdx.x;
  int t = threadIdx.x;
  int node0 = b << BSH;
  int e0 = bucket_off[b], e1 = bucket_off[b + 1];

  degl[t] = 0;
  __syncthreads();
  for (int i = e0 + t; i < e1; i += BNODES) atomicAdd(&degl[packed[i] & (BNODES - 1)], 1);
  __syncthreads();

  int d = degl[t];
  int node = node0 + t;
  if (node < N) dinv[node] = rsqrtf((float)(d + 1));   // +1 self-loop

  scan[t] = d;
  __syncthreads();
  #pragma unroll
  for (int off = 1; off < BNODES; off <<= 1){
    int add = (t >= off) ? scan[t - off] : 0;
    __syncthreads();
    scan[t] += add;
    __syncthreads();
  }
  int excl = scan[t] - d;
  if (node < N) rowptr[node] = e0 + excl;
  cur[t] = excl;
  __syncthreads();

  for (int i = e0 + t; i < e1; i += BNODES){
    unsigned int p = packed[i];
    int pos = atomicAdd(&cur[p & (BNODES - 1)], 1);
    colidx[e0 + pos] = (int)(p >> BSH);
  }
}

// ---------------- GEMM: C[row] = (A[row] @ W) * dinv[row] ----------------

__global__ __launch_bounds__(256) void gemm128_scaled_kernel(
    const float* __restrict__ A, const float* __restrict__ W,
    const float* __restrict__ dinv, float* __restrict__ C, int N)
{
  const int t  = threadIdx.x;
  const int tx = t & 15;        // col group: cols tx*8..+7
  const int ty = t >> 4;        // row group: rows ty*8..+7
  const int row0 = blockIdx.x * 128;

  __shared__ float aT[16][132]; // aT[kk][r] = A[row0+r][k0+kk]
  __shared__ float wS[16][132]; // wS[kk][c] = W[k0+kk][c]

  float acc[8][8];
  #pragma unroll
  for (int r = 0; r < 8; ++r)
    #pragma unroll
    for (int c = 0; c < 8; ++c) acc[r][c] = 0.f;

  for (int k0 = 0; k0 < FEAT; k0 += 16){
    #pragma unroll
    for (int j = 0; j < 8; ++j){
      int r   = ty + j * 16;
      int row = row0 + r;
      float v = 0.f;
      if (row < N) v = A[(size_t)row * FEAT + k0 + tx];
      aT[tx][r] = v;
    }
    #pragma unroll
    for (int i = 0; i < 8; ++i){
      int idx = t + i * 256;
      wS[idx >> 7][idx & 127] = W[(size_t)(k0 + (idx >> 7)) * FEAT + (idx & 127)];
    }
    __syncthreads();
    #pragma unroll
    for (int kk = 0; kk < 16; ++kk){
      float a[8], bb[8];
      #pragma unroll
      for (int r = 0; r < 8; ++r) a[r] = aT[kk][ty * 8 + r];
      #pragma unroll
      for (int c = 0; c < 8; ++c) bb[c] = wS[kk][tx * 8 + c];
      #pragma unroll
      for (int r = 0; r < 8; ++r)
        #pragma unroll
        for (int c = 0; c < 8; ++c) acc[r][c] += a[r] * bb[c];
    }
    __syncthreads();
  }

  #pragma unroll
  for (int r = 0; r < 8; ++r){
    int row = row0 + ty * 8 + r;
    if (row < N){
      float s = dinv[row];
      float* p = &C[(size_t)row * FEAT + tx * 8];
      float4 v0 = make_float4(acc[r][0]*s, acc[r][1]*s, acc[r][2]*s, acc[r][3]*s);
      float4 v1 = make_float4(acc[r][4]*s, acc[r][5]*s, acc[r][6]*s, acc[r][7]*s);
      *reinterpret_cast<float4*>(p)     = v0;
      *reinterpret_cast<float4*>(p + 4) = v1;
    }
  }
}

// ---------------- Aggregation ----------------

__global__ __launch_bounds__(256) void aggregate_kernel(
    const float* __restrict__ Hs, const int* __restrict__ rowptr,
    const int* __restrict__ col, const float* __restrict__ dinv,
    const float* __restrict__ bias, float* __restrict__ out, int N)
{
  int gid  = blockIdx.x * blockDim.x + threadIdx.x;
  int v    = gid >> 6;
  int lane = threadIdx.x & 63;
  if (v >= N) return;
  const float dv = dinv[v];
  int e = rowptr[v], end = rowptr[v + 1];

  float2 acc = *reinterpret_cast<const float2*>(Hs + (size_t)v * FEAT + lane * 2); // self-loop
  for (; e + 4 <= end; e += 4){
    int u0 = col[e], u1 = col[e+1], u2 = col[e+2], u3 = col[e+3];
    float2 p0 = *reinterpret_cast<const float2*>(Hs + (size_t)u0 * FEAT + lane * 2);
    float2 p1 = *reinterpret_cast<const float2*>(Hs + (size_t)u1 * FEAT + lane * 2);
    float2 p2 = *reinterpret_cast<const float2*>(Hs + (size_t)u2 * FEAT + lane * 2);
    float2 p3 = *reinterpret_cast<const float2*>(Hs + (size_t)u3 * FEAT + lane * 2);
    acc.x += p0.x + p1.x + p2.x + p3.x;
    acc.y += p0.y + p1.y + p2.y + p3.y;
  }
  for (; e < end; ++e){
    int u = col[e];
    float2 p = *reinterpret_cast<const float2*>(Hs + (size_t)u * FEAT + lane * 2);
    acc.x += p.x; acc.y += p.y;
  }
  float2 b = *reinterpret_cast<const float2*>(bias + lane * 2);
  float2 o = make_float2(fmaxf(dv * acc.x + b.x, 0.f), fmaxf(dv * acc.y + b.y, 0.f));
  *reinterpret_cast<float2*>(out + (size_t)v * FEAT + lane * 2) = o;
}

__global__ __launch_bounds__(256) void aggregate_final_kernel(
    const float* __restrict__ Hs, const int* __restrict__ rowptr,
    const int* __restrict__ col, const float* __restrict__ dinv,
    const float* __restrict__ bias, const float* __restrict__ Wf,
    const float* __restrict__ bf, float* __restrict__ out, int N)
{
  int gid  = blockIdx.x * blockDim.x + threadIdx.x;
  int v    = gid >> 6;
  int lane = threadIdx.x & 63;
  if (v >= N) return;
  const float dv = dinv[v];
  int e = rowptr[v], end = rowptr[v + 1];

  float2 acc = *reinterpret_cast<const float2*>(Hs + (size_t)v * FEAT + lane * 2);
  for (; e + 4 <= end; e += 4){
    int u0 = col[e], u1 = col[e+1], u2 = col[e+2], u3 = col[e+3];
    float2 p0 = *reinterpret_cast<const float2*>(Hs + (size_t)u0 * FEAT + lane * 2);
    float2 p1 = *reinterpret_cast<const float2*>(Hs + (size_t)u1 * FEAT + lane * 2);
    float2 p2 = *reinterpret_cast<const float2*>(Hs + (size_t)u2 * FEAT + lane * 2);
    float2 p3 = *reinterpret_cast<const float2*>(Hs + (size_t)u3 * FEAT + lane * 2);
    acc.x += p0.x + p1.x + p2.x + p3.x;
    acc.y += p0.y + p1.y + p2.y + p3.y;
  }
  for (; e < end; ++e){
    int u = col[e];
    float2 p = *reinterpret_cast<const float2*>(Hs + (size_t)u * FEAT + lane * 2);
    acc.x += p.x; acc.y += p.y;
  }
  float2 b = *reinterpret_cast<const float2*>(bias + lane * 2);
  float ox = fmaxf(dv * acc.x + b.x, 0.f);
  float oy = fmaxf(dv * acc.y + b.y, 0.f);
  float2 w = *reinterpret_cast<const float2*>(Wf + lane * 2);
  float p = ox * w.x + oy * w.y;
  #pragma unroll
  for (int off = 32; off > 0; off >>= 1) p += __shfl_down(p, off, 64);
  if (lane == 0) out[v] = p + bf[0];
}

// ---------------- launch ----------------

extern "C" void kernel_launch(void* const* d_in, const int* in_sizes, int n_in,
                              void* d_out, int out_size, void* d_ws, size_t ws_size,
                              hipStream_t stream)
{
  const float* x   = (const float*)d_in[0];
  const float* W1  = (const float*)d_in[1];
  const float* b1  = (const float*)d_in[2];
  const float* W2  = (const float*)d_in[3];
  const float* b2  = (const float*)d_in[4];
  const float* Wf  = (const float*)d_in[5];
  const float* bfb = (const float*)d_in[6];
  const int*  eidx = (const int*)d_in[7];

  const int N = in_sizes[0] / FEAT;
  const int E = in_sizes[7] / 2;
  const int* src = eidx;
  const int* dst = eidx + E;
  const int NBK = (N + BNODES - 1) >> BSH;   // 196 buckets

  char* ws = (char*)d_ws;
  size_t off = 0;
  auto alloc = [&](size_t bytes){ void* p = ws + off; off = align_up(off + bytes, 256); return p; };
  float* A        = (float*)alloc((size_t)N * FEAT * 4);   // 51.2 MB
  float* B        = (float*)alloc((size_t)N * FEAT * 4);   // 51.2 MB
  float* dinv     = (float*)alloc((size_t)N * 4);
  int*   rowptr   = (int*)  alloc((size_t)(N + 1) * 4);
  int*   colidx   = (int*)  alloc((size_t)E * 4);          // 6.4 MB
  unsigned int* packed = (unsigned int*)alloc((size_t)E * 4); // 6.4 MB
  int*   bcnt     = (int*)  alloc(256 * 4);
  int*   boff     = (int*)  alloc(257 * 4);
  int*   bcur     = (int*)  alloc(256 * 4);
  (void)ws_size; (void)n_in; (void)out_size;

  const int tb = 256;
  const int PBLK = 256;                       // partition blocks
  const int chunk = (E + PBLK - 1) / PBLK;    // edges per partition block

  hipMemsetAsync(bcnt, 0, 256 * 4, stream);

  bin_count_kernel  <<<PBLK, 256, 0, stream>>>(dst, bcnt, E, chunk);
  bucket_scan_kernel<<<1, 256, 0, stream>>>(bcnt, boff, bcur, rowptr, NBK, N);
  bin_scatter_kernel<<<PBLK, 256, 0, stream>>>(src, dst, bcur, packed, E, chunk);
  bucket_build_kernel<<<NBK, BNODES, 0, stream>>>(packed, boff, dinv, rowptr, colidx, N);

  int gblocks = (N + 127) / 128;
  int ablocks = (int)(((size_t)N * 64 + tb - 1) / tb);   // one wave per node

  gemm128_scaled_kernel<<<gblocks, 256, 0, stream>>>(x, W1, dinv, A, N);
  aggregate_kernel<<<ablocks, tb, 0, stream>>>(A, rowptr, colidx, dinv, b1, B, N);
  gemm128_scaled_kernel<<<gblocks, 256, 0, stream>>>(B, W2, dinv, A, N);
  aggregate_final_kernel<<<ablocks, tb, 0, stream>>>(A, rowptr, colidx, dinv, b2, Wf, bfb,
                                                     (float*)d_out, N);
}

// Round 7
// 344.310 us; speedup vs baseline: 1.9148x; 1.5635x over previous
//
#include <hip/hip_runtime.h>

// GCN x2 + final linear, N=100k, E=1.6M, feat=128.
// fp32 in/out; internal pipeline bf16 (messages + MFMA GEMM), fp32 accum.
//   CSR build: radix partition by dst>>9 (unchanged from R1, verified).
//   wt_convert: W[k][n] fp32 -> Wt[n][k] bf16 (once per W).
//   gemm_mfma<INBF>: C_bf16[row] = bf16( (A[row]*dinv[row]) @ W ), 128x128
//     tile, 4 waves, mfma_f32_16x16x32_bf16, XOR-swizzled LDS fragments.
//   aggregate: out[v] = relu(dinv[v]*(M[v] + sum M[u]) + b)  (bf16 gather,
//     fp32 acc); layer-2 variant fuses the final 128->1 dot (fp32).

#define FEAT 128
#define BSH 9
#define BNODES 512

typedef __attribute__((ext_vector_type(8))) short  bf16x8;
typedef __attribute__((ext_vector_type(4))) float  f32x4;

static inline size_t align_up(size_t x, size_t a){ return (x + a - 1) & ~(a - 1); }

__device__ __forceinline__ unsigned short f2bf(float f){   // RNE round
  unsigned int u = __float_as_uint(f);
  return (unsigned short)((u + 0x7fffu + ((u >> 16) & 1u)) >> 16);
}
__device__ __forceinline__ float bflo(unsigned int p){ return __uint_as_float(p << 16); }
__device__ __forceinline__ float bfhi(unsigned int p){ return __uint_as_float(p & 0xffff0000u); }

// ---------------- CSR build via radix partition ----------------

__global__ __launch_bounds__(256) void bin_count_kernel(
    const int* __restrict__ dst, int* __restrict__ bucket_cnt, int E, int chunk)
{
  __shared__ int hist[256];
  int t = threadIdx.x;
  hist[t] = 0;
  __syncthreads();
  int s0 = blockIdx.x * chunk, s1 = min(E, s0 + chunk);
  for (int i = s0 + t; i < s1; i += 256) atomicAdd(&hist[dst[i] >> BSH], 1);
  __syncthreads();
  if (hist[t] > 0) atomicAdd(&bucket_cnt[t], hist[t]);
}

__global__ __launch_bounds__(256) void bucket_scan_kernel(
    int* __restrict__ bucket_cnt, int* __restrict__ bucket_off,
    int* __restrict__ bucket_cur, int* __restrict__ rowptr, int nbk, int N)
{
  __shared__ int sh[256];
  int t = threadIdx.x;
  int v = (t < nbk) ? bucket_cnt[t] : 0;
  sh[t] = v;
  __syncthreads();
  #pragma unroll
  for (int off = 1; off < 256; off <<= 1){
    int add = (t >= off) ? sh[t - off] : 0;
    __syncthreads();
    sh[t] += add;
    __syncthreads();
  }
  if (t < nbk){
    int e = sh[t] - v;
    bucket_off[t] = e;
    bucket_cur[t] = e;
  }
  if (t == 0){
    bucket_off[nbk] = sh[255];
    rowptr[N] = sh[255];
  }
}

__global__ __launch_bounds__(256) void bin_scatter_kernel(
    const int* __restrict__ src, const int* __restrict__ dst,
    int* __restrict__ bucket_cur, unsigned int* __restrict__ packed, int E, int chunk)
{
  __shared__ int hist[256];
  __shared__ int base[256];
  int t = threadIdx.x;
  hist[t] = 0;
  __syncthreads();
  int s0 = blockIdx.x * chunk, s1 = min(E, s0 + chunk);
  for (int i = s0 + t; i < s1; i += 256) atomicAdd(&hist[dst[i] >> BSH], 1);
  __syncthreads();
  int h = hist[t];
  if (h > 0) base[t] = atomicAdd(&bucket_cur[t], h);
  __syncthreads();
  hist[t] = 0;
  __syncthreads();
  for (int i = s0 + t; i < s1; i += 256){
    int d = dst[i];
    int b = d >> BSH;
    int pos = base[b] + atomicAdd(&hist[b], 1);
    packed[pos] = ((unsigned int)src[i] << BSH) | (unsigned int)(d & (BNODES - 1));
  }
}

__global__ __launch_bounds__(512) void bucket_build_kernel(
    const unsigned int* __restrict__ packed, const int* __restrict__ bucket_off,
    float* __restrict__ dinv, int* __restrict__ rowptr, int* __restrict__ colidx, int N)
{
  __shared__ int degl[BNODES];
  __shared__ int scan[BNODES];
  __shared__ int cur[BNODES];
  int b = blockIdx.x;
  int t = threadIdx.x;
  int node0 = b << BSH;
  int e0 = bucket_off[b], e1 = bucket_off[b + 1];

  degl[t] = 0;
  __syncthreads();
  for (int i = e0 + t; i < e1; i += BNODES) atomicAdd(&degl[packed[i] & (BNODES - 1)], 1);
  __syncthreads();

  int d = degl[t];
  int node = node0 + t;
  if (node < N) dinv[node] = rsqrtf((float)(d + 1));

  scan[t] = d;
  __syncthreads();
  #pragma unroll
  for (int off = 1; off < BNODES; off <<= 1){
    int add = (t >= off) ? scan[t - off] : 0;
    __syncthreads();
    scan[t] += add;
    __syncthreads();
  }
  int excl = scan[t] - d;
  if (node < N) rowptr[node] = e0 + excl;
  cur[t] = excl;
  __syncthreads();

  for (int i = e0 + t; i < e1; i += BNODES){
    unsigned int p = packed[i];
    int pos = atomicAdd(&cur[p & (BNODES - 1)], 1);
    colidx[e0 + pos] = (int)(p >> BSH);
  }
}

// ---------------- W transpose + bf16 convert: Wt[n][k] = bf16(W[k][n]) ----

__global__ __launch_bounds__(256) void wt_convert_kernel(
    const float* __restrict__ W, unsigned short* __restrict__ Wt)
{
  int gid = blockIdx.x * 256 + threadIdx.x;       // 16384 total
  int n = gid >> 7, k = gid & 127;
  Wt[gid] = f2bf(W[(size_t)k * FEAT + n]);
}

// ---------------- MFMA GEMM: Cbf[row] = bf16((A[row]*dinv[row]) @ W) ------
// block: 256 thr / 4 waves; tile M=128 x N=128, K=128 staged whole in LDS.
// Fragment reads are ds_read_b128 with XOR swizzle ^((row&7)<<3) [ushort
// units] to break the 256B-row-stride bank conflict (T2 / G4).

template<bool INBF>
__global__ __launch_bounds__(256) void gemm_mfma_kernel(
    const void* __restrict__ Ain, const unsigned short* __restrict__ Wt,
    const float* __restrict__ dinv, unsigned short* __restrict__ Cout, int N)
{
  __shared__ unsigned short aT[128 * 128];   // [m][k] bf16, swizzled
  __shared__ unsigned short wT[128 * 128];   // [n][k] bf16, swizzled
  const int t = threadIdx.x;
  const int row0 = blockIdx.x * 128;

  // stage Wt (32 KB) -> wT
  {
    const uint4* s4 = (const uint4*)Wt;          // 2048 16B chunks
    #pragma unroll
    for (int i = 0; i < 8; ++i){
      int c = t + i * 256;
      int n = c >> 4, k8 = (c & 15) * 8;
      uint4 v = s4[c];
      *reinterpret_cast<uint4*>(&wT[(n * 128 + k8) ^ ((n & 7) << 3)]) = v;
    }
  }
  // stage A rows (scaled by dinv, bf16) -> aT
  if (INBF){
    const unsigned short* Ab = (const unsigned short*)Ain;
    #pragma unroll
    for (int i = 0; i < 8; ++i){
      int c = t + i * 256;
      int r = c >> 4, k8 = (c & 15) * 8;
      int row = row0 + r;
      uint4 v = make_uint4(0, 0, 0, 0);
      float s = 0.f;
      if (row < N){ v = *(const uint4*)(Ab + (size_t)row * FEAT + k8); s = dinv[row]; }
      unsigned int wi[4] = {v.x, v.y, v.z, v.w}, o[4];
      #pragma unroll
      for (int j = 0; j < 4; ++j){
        float lo = bflo(wi[j]) * s, hi = bfhi(wi[j]) * s;
        o[j] = (unsigned int)f2bf(lo) | ((unsigned int)f2bf(hi) << 16);
      }
      *reinterpret_cast<uint4*>(&aT[(r * 128 + k8) ^ ((r & 7) << 3)]) = make_uint4(o[0], o[1], o[2], o[3]);
    }
  } else {
    const float* Af = (const float*)Ain;
    #pragma unroll
    for (int i = 0; i < 16; ++i){
      int c = t + i * 256;                       // 4096 chunks of 4 floats
      int r = c >> 5, k4 = (c & 31) * 4;
      int row = row0 + r;
      float4 v = make_float4(0, 0, 0, 0);
      float s = 0.f;
      if (row < N){ v = *(const float4*)(Af + (size_t)row * FEAT + k4); s = dinv[row]; }
      ushort4 o;
      o.x = f2bf(v.x * s); o.y = f2bf(v.y * s); o.z = f2bf(v.z * s); o.w = f2bf(v.w * s);
      *reinterpret_cast<ushort4*>(&aT[(r * 128 + k4) ^ ((r & 7) << 3)]) = o;
    }
  }
  __syncthreads();

  const int w = t >> 6, l = t & 63;
  const int wbase = w * 32;
  const int lm = l & 15;
  const int lk = (l >> 4) * 8;

  f32x4 acc[8][2];
  #pragma unroll
  for (int mt = 0; mt < 8; ++mt)
    #pragma unroll
    for (int nt = 0; nt < 2; ++nt) acc[mt][nt] = (f32x4){0.f, 0.f, 0.f, 0.f};

  #pragma unroll
  for (int ks = 0; ks < 4; ++ks){
    int kb = ks * 32 + lk;
    bf16x8 bfr[2], afr[8];
    #pragma unroll
    for (int nt = 0; nt < 2; ++nt){
      int n = wbase + nt * 16 + lm;
      bfr[nt] = *reinterpret_cast<const bf16x8*>(&wT[(n * 128 + kb) ^ ((n & 7) << 3)]);
    }
    #pragma unroll
    for (int mt = 0; mt < 8; ++mt){
      int m = mt * 16 + lm;
      afr[mt] = *reinterpret_cast<const bf16x8*>(&aT[(m * 128 + kb) ^ ((m & 7) << 3)]);
    }
    #pragma unroll
    for (int mt = 0; mt < 8; ++mt)
      #pragma unroll
      for (int nt = 0; nt < 2; ++nt)
        acc[mt][nt] = __builtin_amdgcn_mfma_f32_16x16x32_bf16(afr[mt], bfr[nt], acc[mt][nt], 0, 0, 0);
  }
  __syncthreads();

  // repack D (col=lane&15, row=(lane>>4)*4+reg) -> aT linear, then coalesced store
  #pragma unroll
  for (int mt = 0; mt < 8; ++mt)
    #pragma unroll
    for (int nt = 0; nt < 2; ++nt)
      #pragma unroll
      for (int r = 0; r < 4; ++r){
        int mrow = mt * 16 + (l >> 4) * 4 + r;
        int col  = wbase + nt * 16 + lm;
        aT[mrow * 128 + col] = f2bf(acc[mt][nt][r]);
      }
  __syncthreads();
  #pragma unroll
  for (int i = 0; i < 8; ++i){
    int c = t + i * 256;
    int r = c >> 4, k8 = (c & 15) * 8;
    int row = row0 + r;
    if (row < N)
      *reinterpret_cast<uint4*>(&Cout[(size_t)row * FEAT + k8]) =
          *reinterpret_cast<const uint4*>(&aT[r * 128 + k8]);
  }
}

// ---------------- Aggregation (bf16 messages, fp32 accum) ----------------

__global__ __launch_bounds__(256) void aggregate_kernel(
    const unsigned short* __restrict__ Hs, const int* __restrict__ rowptr,
    const int* __restrict__ col, const float* __restrict__ dinv,
    const float* __restrict__ bias, unsigned short* __restrict__ out, int N)
{
  int gid  = blockIdx.x * blockDim.x + threadIdx.x;
  int v    = gid >> 6;
  int lane = threadIdx.x & 63;
  if (v >= N) return;
  const float dv = dinv[v];
  const unsigned int* Hu = (const unsigned int*)Hs;   // 2 bf16 per lane
  int e = rowptr[v], end = rowptr[v + 1];

  unsigned int m = Hu[(size_t)v * 64 + lane];         // self-loop
  float ax = bflo(m), ay = bfhi(m);
  for (; e + 4 <= end; e += 4){
    int u0 = col[e], u1 = col[e + 1], u2 = col[e + 2], u3 = col[e + 3];
    unsigned int p0 = Hu[(size_t)u0 * 64 + lane];
    unsigned int p1 = Hu[(size_t)u1 * 64 + lane];
    unsigned int p2 = Hu[(size_t)u2 * 64 + lane];
    unsigned int p3 = Hu[(size_t)u3 * 64 + lane];
    ax += bflo(p0) + bflo(p1) + bflo(p2) + bflo(p3);
    ay += bfhi(p0) + bfhi(p1) + bfhi(p2) + bfhi(p3);
  }
  for (; e < end; ++e){
    unsigned int p = Hu[(size_t)col[e] * 64 + lane];
    ax += bflo(p); ay += bfhi(p);
  }
  float2 b = *reinterpret_cast<const float2*>(bias + lane * 2);
  float ox = fmaxf(dv * ax + b.x, 0.f);
  float oy = fmaxf(dv * ay + b.y, 0.f);
  ((unsigned int*)out)[(size_t)v * 64 + lane] =
      (unsigned int)f2bf(ox) | ((unsigned int)f2bf(oy) << 16);
}

__global__ __launch_bounds__(256) void aggregate_final_kernel(
    const unsigned short* __restrict__ Hs, const int* __restrict__ rowptr,
    const int* __restrict__ col, const float* __restrict__ dinv,
    const float* __restrict__ bias, const float* __restrict__ Wf,
    const float* __restrict__ bf, float* __restrict__ out, int N)
{
  int gid  = blockIdx.x * blockDim.x + threadIdx.x;
  int v    = gid >> 6;
  int lane = threadIdx.x & 63;
  if (v >= N) return;
  const float dv = dinv[v];
  const unsigned int* Hu = (const unsigned int*)Hs;
  int e = rowptr[v], end = rowptr[v + 1];

  unsigned int m = Hu[(size_t)v * 64 + lane];
  float ax = bflo(m), ay = bfhi(m);
  for (; e + 4 <= end; e += 4){
    int u0 = col[e], u1 = col[e + 1], u2 = col[e + 2], u3 = col[e + 3];
    unsigned int p0 = Hu[(size_t)u0 * 64 + lane];
    unsigned int p1 = Hu[(size_t)u1 * 64 + lane];
    unsigned int p2 = Hu[(size_t)u2 * 64 + lane];
    unsigned int p3 = Hu[(size_t)u3 * 64 + lane];
    ax += bflo(p0) + bflo(p1) + bflo(p2) + bflo(p3);
    ay += bfhi(p0) + bfhi(p1) + bfhi(p2) + bfhi(p3);
  }
  for (; e < end; ++e){
    unsigned int p = Hu[(size_t)col[e] * 64 + lane];
    ax += bflo(p); ay += bfhi(p);
  }
  float2 b = *reinterpret_cast<const float2*>(bias + lane * 2);
  float ox = fmaxf(dv * ax + b.x, 0.f);
  float oy = fmaxf(dv * ay + b.y, 0.f);
  float2 wf = *reinterpret_cast<const float2*>(Wf + lane * 2);
  float p = ox * wf.x + oy * wf.y;
  #pragma unroll
  for (int off = 32; off > 0; off >>= 1) p += __shfl_down(p, off, 64);
  if (lane == 0) out[v] = p + bf[0];
}

// ---------------- launch ----------------

extern "C" void kernel_launch(void* const* d_in, const int* in_sizes, int n_in,
                              void* d_out, int out_size, void* d_ws, size_t ws_size,
                              hipStream_t stream)
{
  const float* x   = (const float*)d_in[0];
  const float* W1  = (const float*)d_in[1];
  const float* b1  = (const float*)d_in[2];
  const float* W2  = (const float*)d_in[3];
  const float* b2  = (const float*)d_in[4];
  const float* Wf  = (const float*)d_in[5];
  const float* bfb = (const float*)d_in[6];
  const int*  eidx = (const int*)d_in[7];

  const int N = in_sizes[0] / FEAT;
  const int E = in_sizes[7] / 2;
  const int* src = eidx;
  const int* dst = eidx + E;
  const int NBK = (N + BNODES - 1) >> BSH;

  char* ws = (char*)d_ws;
  size_t off = 0;
  auto alloc = [&](size_t bytes){ void* p = ws + off; off = align_up(off + bytes, 256); return p; };
  unsigned short* A    = (unsigned short*)alloc((size_t)N * FEAT * 2);  // 25.6 MB msgs
  unsigned short* B    = (unsigned short*)alloc((size_t)N * FEAT * 2);  // 25.6 MB act
  unsigned short* Wt1  = (unsigned short*)alloc((size_t)FEAT * FEAT * 2);
  unsigned short* Wt2  = (unsigned short*)alloc((size_t)FEAT * FEAT * 2);
  float* dinv   = (float*)alloc((size_t)N * 4);
  int*   rowptr = (int*)  alloc((size_t)(N + 1) * 4);
  int*   colidx = (int*)  alloc((size_t)E * 4);
  unsigned int* packed = (unsigned int*)alloc((size_t)E * 4);
  int*   bcnt   = (int*)  alloc(256 * 4);
  int*   boff   = (int*)  alloc(257 * 4);
  int*   bcur   = (int*)  alloc(256 * 4);
  (void)ws_size; (void)n_in; (void)out_size;

  const int tb = 256;
  const int PBLK = 256;
  const int chunk = (E + PBLK - 1) / PBLK;

  hipMemsetAsync(bcnt, 0, 256 * 4, stream);

  bin_count_kernel  <<<PBLK, 256, 0, stream>>>(dst, bcnt, E, chunk);
  bucket_scan_kernel<<<1, 256, 0, stream>>>(bcnt, boff, bcur, rowptr, NBK, N);
  bin_scatter_kernel<<<PBLK, 256, 0, stream>>>(src, dst, bcur, packed, E, chunk);
  bucket_build_kernel<<<NBK, BNODES, 0, stream>>>(packed, boff, dinv, rowptr, colidx, N);

  wt_convert_kernel<<<64, 256, 0, stream>>>(W1, Wt1);
  wt_convert_kernel<<<64, 256, 0, stream>>>(W2, Wt2);

  int gblocks = (N + 127) / 128;
  int ablocks = (int)(((size_t)N * 64 + tb - 1) / tb);

  gemm_mfma_kernel<false><<<gblocks, 256, 0, stream>>>(x, Wt1, dinv, A, N);
  aggregate_kernel<<<ablocks, tb, 0, stream>>>(A, rowptr, colidx, dinv, b1, B, N);
  gemm_mfma_kernel<true><<<gblocks, 256, 0, stream>>>(B, Wt2, dinv, A, N);
  aggregate_final_kernel<<<ablocks, tb, 0, stream>>>(A, rowptr, colidx, dinv, b2, Wf, bfb,
                                                     (float*)d_out, N);
}

// Round 10
// 323.839 us; speedup vs baseline: 2.0359x; 1.0632x over previous
//
#include <hip/hip_runtime.h>

// GCN x2 + final linear, N=100k, E=1.6M, feat=128.
// fp32 in/out; internal pipeline bf16 (messages + MFMA GEMM), fp32 accum.
// This round: aggregates restructured for latency-hiding — two 32-lane
// half-waves gather different edges (uint2 = 4 features/lane), 8-deep
// unroll per half = 16 gathers in flight per wave.

#define FEAT 128
#define BSH 9
#define BNODES 512

typedef __attribute__((ext_vector_type(8))) short  bf16x8;
typedef __attribute__((ext_vector_type(4))) float  f32x4;

static inline size_t align_up(size_t x, size_t a){ return (x + a - 1) & ~(a - 1); }

__device__ __forceinline__ unsigned short f2bf(float f){   // RNE round
  unsigned int u = __float_as_uint(f);
  return (unsigned short)((u + 0x7fffu + ((u >> 16) & 1u)) >> 16);
}
__device__ __forceinline__ float bflo(unsigned int p){ return __uint_as_float(p << 16); }
__device__ __forceinline__ float bfhi(unsigned int p){ return __uint_as_float(p & 0xffff0000u); }

// ---------------- CSR build via radix partition ----------------

__global__ __launch_bounds__(256) void bin_count_kernel(
    const int* __restrict__ dst, int* __restrict__ bucket_cnt, int E, int chunk)
{
  __shared__ int hist[256];
  int t = threadIdx.x;
  hist[t] = 0;
  __syncthreads();
  int s0 = blockIdx.x * chunk, s1 = min(E, s0 + chunk);
  for (int i = s0 + t; i < s1; i += 256) atomicAdd(&hist[dst[i] >> BSH], 1);
  __syncthreads();
  if (hist[t] > 0) atomicAdd(&bucket_cnt[t], hist[t]);
}

__global__ __launch_bounds__(256) void bucket_scan_kernel(
    int* __restrict__ bucket_cnt, int* __restrict__ bucket_off,
    int* __restrict__ bucket_cur, int* __restrict__ rowptr, int nbk, int N)
{
  __shared__ int sh[256];
  int t = threadIdx.x;
  int v = (t < nbk) ? bucket_cnt[t] : 0;
  sh[t] = v;
  __syncthreads();
  #pragma unroll
  for (int off = 1; off < 256; off <<= 1){
    int add = (t >= off) ? sh[t - off] : 0;
    __syncthreads();
    sh[t] += add;
    __syncthreads();
  }
  if (t < nbk){
    int e = sh[t] - v;
    bucket_off[t] = e;
    bucket_cur[t] = e;
  }
  if (t == 0){
    bucket_off[nbk] = sh[255];
    rowptr[N] = sh[255];
  }
}

__global__ __launch_bounds__(256) void bin_scatter_kernel(
    const int* __restrict__ src, const int* __restrict__ dst,
    int* __restrict__ bucket_cur, unsigned int* __restrict__ packed, int E, int chunk)
{
  __shared__ int hist[256];
  __shared__ int base[256];
  int t = threadIdx.x;
  hist[t] = 0;
  __syncthreads();
  int s0 = blockIdx.x * chunk, s1 = min(E, s0 + chunk);
  for (int i = s0 + t; i < s1; i += 256) atomicAdd(&hist[dst[i] >> BSH], 1);
  __syncthreads();
  int h = hist[t];
  if (h > 0) base[t] = atomicAdd(&bucket_cur[t], h);
  __syncthreads();
  hist[t] = 0;
  __syncthreads();
  for (int i = s0 + t; i < s1; i += 256){
    int d = dst[i];
    int b = d >> BSH;
    int pos = base[b] + atomicAdd(&hist[b], 1);
    packed[pos] = ((unsigned int)src[i] << BSH) | (unsigned int)(d & (BNODES - 1));
  }
}

__global__ __launch_bounds__(512) void bucket_build_kernel(
    const unsigned int* __restrict__ packed, const int* __restrict__ bucket_off,
    float* __restrict__ dinv, int* __restrict__ rowptr, int* __restrict__ colidx, int N)
{
  __shared__ int degl[BNODES];
  __shared__ int scan[BNODES];
  __shared__ int cur[BNODES];
  int b = blockIdx.x;
  int t = threadIdx.x;
  int node0 = b << BSH;
  int e0 = bucket_off[b], e1 = bucket_off[b + 1];

  degl[t] = 0;
  __syncthreads();
  for (int i = e0 + t; i < e1; i += BNODES) atomicAdd(&degl[packed[i] & (BNODES - 1)], 1);
  __syncthreads();

  int d = degl[t];
  int node = node0 + t;
  if (node < N) dinv[node] = rsqrtf((float)(d + 1));

  scan[t] = d;
  __syncthreads();
  #pragma unroll
  for (int off = 1; off < BNODES; off <<= 1){
    int add = (t >= off) ? scan[t - off] : 0;
    __syncthreads();
    scan[t] += add;
    __syncthreads();
  }
  int excl = scan[t] - d;
  if (node < N) rowptr[node] = e0 + excl;
  cur[t] = excl;
  __syncthreads();

  for (int i = e0 + t; i < e1; i += BNODES){
    unsigned int p = packed[i];
    int pos = atomicAdd(&cur[p & (BNODES - 1)], 1);
    colidx[e0 + pos] = (int)(p >> BSH);
  }
}

// ---------------- W transpose + bf16 convert: Wt[n][k] = bf16(W[k][n]) ----

__global__ __launch_bounds__(256) void wt_convert_kernel(
    const float* __restrict__ W, unsigned short* __restrict__ Wt)
{
  int gid = blockIdx.x * 256 + threadIdx.x;       // 16384 total
  int n = gid >> 7, k = gid & 127;
  Wt[gid] = f2bf(W[(size_t)k * FEAT + n]);
}

// ---------------- MFMA GEMM: Cbf[row] = bf16((A[row]*dinv[row]) @ W) ------

template<bool INBF>
__global__ __launch_bounds__(256) void gemm_mfma_kernel(
    const void* __restrict__ Ain, const unsigned short* __restrict__ Wt,
    const float* __restrict__ dinv, unsigned short* __restrict__ Cout, int N)
{
  __shared__ unsigned short aT[128 * 128];   // [m][k] bf16, swizzled
  __shared__ unsigned short wT[128 * 128];   // [n][k] bf16, swizzled
  const int t = threadIdx.x;
  const int row0 = blockIdx.x * 128;

  {
    const uint4* s4 = (const uint4*)Wt;          // 2048 16B chunks
    #pragma unroll
    for (int i = 0; i < 8; ++i){
      int c = t + i * 256;
      int n = c >> 4, k8 = (c & 15) * 8;
      uint4 v = s4[c];
      *reinterpret_cast<uint4*>(&wT[(n * 128 + k8) ^ ((n & 7) << 3)]) = v;
    }
  }
  if (INBF){
    const unsigned short* Ab = (const unsigned short*)Ain;
    #pragma unroll
    for (int i = 0; i < 8; ++i){
      int c = t + i * 256;
      int r = c >> 4, k8 = (c & 15) * 8;
      int row = row0 + r;
      uint4 v = make_uint4(0, 0, 0, 0);
      float s = 0.f;
      if (row < N){ v = *(const uint4*)(Ab + (size_t)row * FEAT + k8); s = dinv[row]; }
      unsigned int wi[4] = {v.x, v.y, v.z, v.w}, o[4];
      #pragma unroll
      for (int j = 0; j < 4; ++j){
        float lo = bflo(wi[j]) * s, hi = bfhi(wi[j]) * s;
        o[j] = (unsigned int)f2bf(lo) | ((unsigned int)f2bf(hi) << 16);
      }
      *reinterpret_cast<uint4*>(&aT[(r * 128 + k8) ^ ((r & 7) << 3)]) = make_uint4(o[0], o[1], o[2], o[3]);
    }
  } else {
    const float* Af = (const float*)Ain;
    #pragma unroll
    for (int i = 0; i < 16; ++i){
      int c = t + i * 256;                       // 4096 chunks of 4 floats
      int r = c >> 5, k4 = (c & 31) * 4;
      int row = row0 + r;
      float4 v = make_float4(0, 0, 0, 0);
      float s = 0.f;
      if (row < N){ v = *(const float4*)(Af + (size_t)row * FEAT + k4); s = dinv[row]; }
      ushort4 o;
      o.x = f2bf(v.x * s); o.y = f2bf(v.y * s); o.z = f2bf(v.z * s); o.w = f2bf(v.w * s);
      *reinterpret_cast<ushort4*>(&aT[(r * 128 + k4) ^ ((r & 7) << 3)]) = o;
    }
  }
  __syncthreads();

  const int w = t >> 6, l = t & 63;
  const int wbase = w * 32;
  const int lm = l & 15;
  const int lk = (l >> 4) * 8;

  f32x4 acc[8][2];
  #pragma unroll
  for (int mt = 0; mt < 8; ++mt)
    #pragma unroll
    for (int nt = 0; nt < 2; ++nt) acc[mt][nt] = (f32x4){0.f, 0.f, 0.f, 0.f};

  #pragma unroll
  for (int ks = 0; ks < 4; ++ks){
    int kb = ks * 32 + lk;
    bf16x8 bfr[2], afr[8];
    #pragma unroll
    for (int nt = 0; nt < 2; ++nt){
      int n = wbase + nt * 16 + lm;
      bfr[nt] = *reinterpret_cast<const bf16x8*>(&wT[(n * 128 + kb) ^ ((n & 7) << 3)]);
    }
    #pragma unroll
    for (int mt = 0; mt < 8; ++mt){
      int m = mt * 16 + lm;
      afr[mt] = *reinterpret_cast<const bf16x8*>(&aT[(m * 128 + kb) ^ ((m & 7) << 3)]);
    }
    #pragma unroll
    for (int mt = 0; mt < 8; ++mt)
      #pragma unroll
      for (int nt = 0; nt < 2; ++nt)
        acc[mt][nt] = __builtin_amdgcn_mfma_f32_16x16x32_bf16(afr[mt], bfr[nt], acc[mt][nt], 0, 0, 0);
  }
  __syncthreads();

  #pragma unroll
  for (int mt = 0; mt < 8; ++mt)
    #pragma unroll
    for (int nt = 0; nt < 2; ++nt)
      #pragma unroll
      for (int r = 0; r < 4; ++r){
        int mrow = mt * 16 + (l >> 4) * 4 + r;
        int col  = wbase + nt * 16 + lm;
        aT[mrow * 128 + col] = f2bf(acc[mt][nt][r]);
      }
  __syncthreads();
  #pragma unroll
  for (int i = 0; i < 8; ++i){
    int c = t + i * 256;
    int r = c >> 4, k8 = (c & 15) * 8;
    int row = row0 + r;
    if (row < N)
      *reinterpret_cast<uint4*>(&Cout[(size_t)row * FEAT + k8]) =
          *reinterpret_cast<const uint4*>(&aT[r * 128 + k8]);
  }
}

// ---------------- Aggregation (bf16 msgs, fp32 acc, half-wave edges) ------
// Wave per node. Halves (lanes 0-31 / 32-63) process interleaved edges;
// lane covers 4 features via one uint2 (8B) gather. 8-deep unroll per half
// = 16 gathers in flight per wave. Halves merged with one shfl_xor(32).

#define AGG_BODY(Hq, vrow)                                                    \
  float a0 = 0.f, a1 = 0.f, a2 = 0.f, a3 = 0.f;                               \
  if (half == 0){                                                             \
    uint2 s = Hq[(size_t)(vrow) * 32 + hl];                                   \
    a0 = bflo(s.x); a1 = bfhi(s.x); a2 = bflo(s.y); a3 = bfhi(s.y);           \
  }                                                                           \
  int i = e0 + half;                                                          \
  for (; i + 14 < end; i += 16){                                              \
    int u0=col[i],u1=col[i+2],u2=col[i+4],u3=col[i+6];                        \
    int u4=col[i+8],u5=col[i+10],u6=col[i+12],u7=col[i+14];                   \
    uint2 p0=Hq[(size_t)u0*32+hl], p1=Hq[(size_t)u1*32+hl];                   \
    uint2 p2=Hq[(size_t)u2*32+hl], p3=Hq[(size_t)u3*32+hl];                   \
    uint2 p4=Hq[(size_t)u4*32+hl], p5=Hq[(size_t)u5*32+hl];                   \
    uint2 p6=Hq[(size_t)u6*32+hl], p7=Hq[(size_t)u7*32+hl];                   \
    a0 += bflo(p0.x)+bflo(p1.x)+bflo(p2.x)+bflo(p3.x)                         \
        + bflo(p4.x)+bflo(p5.x)+bflo(p6.x)+bflo(p7.x);                        \
    a1 += bfhi(p0.x)+bfhi(p1.x)+bfhi(p2.x)+bfhi(p3.x)                         \
        + bfhi(p4.x)+bfhi(p5.x)+bfhi(p6.x)+bfhi(p7.x);                        \
    a2 += bflo(p0.y)+bflo(p1.y)+bflo(p2.y)+bflo(p3.y)                         \
        + bflo(p4.y)+bflo(p5.y)+bflo(p6.y)+bflo(p7.y);                        \
    a3 += bfhi(p0.y)+bfhi(p1.y)+bfhi(p2.y)+bfhi(p3.y)                         \
        + bfhi(p4.y)+bfhi(p5.y)+bfhi(p6.y)+bfhi(p7.y);                        \
  }                                                                           \
  for (; i + 6 < end; i += 8){                                                \
    int u0=col[i],u1=col[i+2],u2=col[i+4],u3=col[i+6];                        \
    uint2 p0=Hq[(size_t)u0*32+hl], p1=Hq[(size_t)u1*32+hl];                   \
    uint2 p2=Hq[(size_t)u2*32+hl], p3=Hq[(size_t)u3*32+hl];                   \
    a0 += bflo(p0.x)+bflo(p1.x)+bflo(p2.x)+bflo(p3.x);                        \
    a1 += bfhi(p0.x)+bfhi(p1.x)+bfhi(p2.x)+bfhi(p3.x);                        \
    a2 += bflo(p0.y)+bflo(p1.y)+bflo(p2.y)+bflo(p3.y);                        \
    a3 += bfhi(p0.y)+bfhi(p1.y)+bfhi(p2.y)+bfhi(p3.y);                        \
  }                                                                           \
  for (; i < end; i += 2){                                                    \
    uint2 p = Hq[(size_t)col[i]*32 + hl];                                     \
    a0 += bflo(p.x); a1 += bfhi(p.x); a2 += bflo(p.y); a3 += bfhi(p.y);       \
  }                                                                           \
  a0 += __shfl_xor(a0, 32, 64); a1 += __shfl_xor(a1, 32, 64);                 \
  a2 += __shfl_xor(a2, 32, 64); a3 += __shfl_xor(a3, 32, 64);

__global__ __launch_bounds__(256) void aggregate_kernel(
    const unsigned short* __restrict__ Hs, const int* __restrict__ rowptr,
    const int* __restrict__ col, const float* __restrict__ dinv,
    const float* __restrict__ bias, unsigned short* __restrict__ out, int N)
{
  int gid  = blockIdx.x * blockDim.x + threadIdx.x;
  int v    = gid >> 6;
  if (v >= N) return;
  int lane = threadIdx.x & 63;
  int half = lane >> 5;
  int hl   = lane & 31;
  const uint2* Hq = (const uint2*)Hs;
  int e0 = rowptr[v], end = rowptr[v + 1];

  AGG_BODY(Hq, v)

  if (half == 0){
    float dv = dinv[v];
    float4 b = reinterpret_cast<const float4*>(bias)[hl];
    float o0 = fmaxf(dv * a0 + b.x, 0.f);
    float o1 = fmaxf(dv * a1 + b.y, 0.f);
    float o2 = fmaxf(dv * a2 + b.z, 0.f);
    float o3 = fmaxf(dv * a3 + b.w, 0.f);
    uint2 o;
    o.x = (unsigned int)f2bf(o0) | ((unsigned int)f2bf(o1) << 16);
    o.y = (unsigned int)f2bf(o2) | ((unsigned int)f2bf(o3) << 16);
    reinterpret_cast<uint2*>(out)[(size_t)v * 32 + hl] = o;
  }
}

__global__ __launch_bounds__(256) void aggregate_final_kernel(
    const unsigned short* __restrict__ Hs, const int* __restrict__ rowptr,
    const int* __restrict__ col, const float* __restrict__ dinv,
    const float* __restrict__ bias, const float* __restrict__ Wf,
    const float* __restrict__ bf, float* __restrict__ out, int N)
{
  int gid  = blockIdx.x * blockDim.x + threadIdx.x;
  int v    = gid >> 6;
  if (v >= N) return;
  int lane = threadIdx.x & 63;
  int half = lane >> 5;
  int hl   = lane & 31;
  const uint2* Hq = (const uint2*)Hs;
  int e0 = rowptr[v], end = rowptr[v + 1];

  AGG_BODY(Hq, v)

  if (half == 0){
    float dv = dinv[v];
    float4 b  = reinterpret_cast<const float4*>(bias)[hl];
    float4 wf = reinterpret_cast<const float4*>(Wf)[hl];
    float o0 = fmaxf(dv * a0 + b.x, 0.f);
    float o1 = fmaxf(dv * a1 + b.y, 0.f);
    float o2 = fmaxf(dv * a2 + b.z, 0.f);
    float o3 = fmaxf(dv * a3 + b.w, 0.f);
    float p = o0 * wf.x + o1 * wf.y + o2 * wf.z + o3 * wf.w;
    #pragma unroll
    for (int off = 16; off > 0; off >>= 1) p += __shfl_down(p, off, 32);
    if (hl == 0) out[v] = p + bf[0];
  }
}

// ---------------- launch ----------------

extern "C" void kernel_launch(void* const* d_in, const int* in_sizes, int n_in,
                              void* d_out, int out_size, void* d_ws, size_t ws_size,
                              hipStream_t stream)
{
  const float* x   = (const float*)d_in[0];
  const float* W1  = (const float*)d_in[1];
  const float* b1  = (const float*)d_in[2];
  const float* W2  = (const float*)d_in[3];
  const float* b2  = (const float*)d_in[4];
  const float* Wf  = (const float*)d_in[5];
  const float* bfb = (const float*)d_in[6];
  const int*  eidx = (const int*)d_in[7];

  const int N = in_sizes[0] / FEAT;
  const int E = in_sizes[7] / 2;
  const int* src = eidx;
  const int* dst = eidx + E;
  const int NBK = (N + BNODES - 1) >> BSH;

  char* ws = (char*)d_ws;
  size_t off = 0;
  auto alloc = [&](size_t bytes){ void* p = ws + off; off = align_up(off + bytes, 256); return p; };
  unsigned short* A    = (unsigned short*)alloc((size_t)N * FEAT * 2);
  unsigned short* B    = (unsigned short*)alloc((size_t)N * FEAT * 2);
  unsigned short* Wt1  = (unsigned short*)alloc((size_t)FEAT * FEAT * 2);
  unsigned short* Wt2  = (unsigned short*)alloc((size_t)FEAT * FEAT * 2);
  float* dinv   = (float*)alloc((size_t)N * 4);
  int*   rowptr = (int*)  alloc((size_t)(N + 1) * 4);
  int*   colidx = (int*)  alloc((size_t)E * 4);
  unsigned int* packed = (unsigned int*)alloc((size_t)E * 4);
  int*   bcnt   = (int*)  alloc(256 * 4);
  int*   boff   = (int*)  alloc(257 * 4);
  int*   bcur   = (int*)  alloc(256 * 4);
  (void)ws_size; (void)n_in; (void)out_size;

  const int tb = 256;
  const int PBLK = 256;
  const int chunk = (E + PBLK - 1) / PBLK;

  hipMemsetAsync(bcnt, 0, 256 * 4, stream);

  bin_count_kernel  <<<PBLK, 256, 0, stream>>>(dst, bcnt, E, chunk);
  bucket_scan_kernel<<<1, 256, 0, stream>>>(bcnt, boff, bcur, rowptr, NBK, N);
  bin_scatter_kernel<<<PBLK, 256, 0, stream>>>(src, dst, bcur, packed, E, chunk);
  bucket_build_kernel<<<NBK, BNODES, 0, stream>>>(packed, boff, dinv, rowptr, colidx, N);

  wt_convert_kernel<<<64, 256, 0, stream>>>(W1, Wt1);
  wt_convert_kernel<<<64, 256, 0, stream>>>(W2, Wt2);

  int gblocks = (N + 127) / 128;
  int ablocks = (int)(((size_t)N * 64 + tb - 1) / tb);

  gemm_mfma_kernel<false><<<gblocks, 256, 0, stream>>>(x, Wt1, dinv, A, N);
  aggregate_kernel<<<ablocks, tb, 0, stream>>>(A, rowptr, colidx, dinv, b1, B, N);
  gemm_mfma_kernel<true><<<gblocks, 256, 0, stream>>>(B, Wt2, dinv, A, N);
  aggregate_final_kernel<<<ablocks, tb, 0, stream>>>(A, rowptr, colidx, dinv, b2, Wf, bfb,
                                                     (float*)d_out, N);
}